// Round 1
// baseline (1618.804 us; speedup 1.0000x reference)
//
#include <hip/hip_runtime.h>

#define N_NODES 100000
#define D_IN 64
#define HID 128
#define N_EDGES 1600000
#define N_LBL 500000

// ---------------- degree ----------------
__global__ __launch_bounds__(256) void k_deg(const int* __restrict__ dst,
                                             float* __restrict__ deg) {
  int e = blockIdx.x * 256 + threadIdx.x;
  if (e < N_EDGES) atomicAdd(&deg[dst[e]], 1.0f);
}

__global__ __launch_bounds__(256) void k_inv(float* deg) {
  int i = blockIdx.x * 256 + threadIdx.x;
  if (i < N_NODES) {
    float d = deg[i];
    deg[i] = d > 0.0f ? 1.0f / d : 0.0f;
  }
}

// ---------------- scatter-add: agg[dst] += feat[src] ----------------
template <int D>
__global__ __launch_bounds__(256) void k_scatter(const int* __restrict__ src,
                                                 const int* __restrict__ dst,
                                                 const float* __restrict__ feat,
                                                 float* __restrict__ agg) {
  long tid = (long)blockIdx.x * 256 + threadIdx.x;
  int e = (int)(tid >> (D == 64 ? 6 : 7));
  int k = (int)(tid & (D - 1));
  if (e < N_EDGES) {
    int s = src[e], d = dst[e];
    atomicAdd(&agg[(long)d * D + k], feat[(long)s * D + k]);
  }
}

// ---------------- fused SAGE layer: out = act((agg*inv)@wl + bl + in@wr) ----------------
template <int K, bool RELU>
__global__ __launch_bounds__(256) void k_layer(const float* __restrict__ agg,
                                               const float* __restrict__ inv,
                                               const float* __restrict__ xin,
                                               const float* __restrict__ wl,
                                               const float* __restrict__ bl,
                                               const float* __restrict__ wr,
                                               float* __restrict__ out) {
  __shared__ float s_a[8][K];
  __shared__ float s_x[8][K];
  const int col = threadIdx.x & 127;
  const int rsub = threadIdx.x >> 7;  // 0..1
  const long row0 = (long)blockIdx.x * 8;

  for (int idx = threadIdx.x; idx < 8 * K; idx += 256) {
    int r = idx / K, k = idx - r * K;
    long row = row0 + r;
    if (row < N_NODES) {
      float iv = inv[row];
      s_a[r][k] = agg[row * K + k] * iv;
      s_x[r][k] = xin[row * K + k];
    }
  }
  __syncthreads();

  float acc[4];
  float b = bl[col];
#pragma unroll
  for (int i = 0; i < 4; i++) acc[i] = b;

  for (int k = 0; k < K; k++) {
    float wlv = wl[k * HID + col];
    float wrv = wr[k * HID + col];
#pragma unroll
    for (int i = 0; i < 4; i++) {
      int r = rsub + 2 * i;
      acc[i] = fmaf(s_a[r][k], wlv, acc[i]);
      acc[i] = fmaf(s_x[r][k], wrv, acc[i]);
    }
  }

#pragma unroll
  for (int i = 0; i < 4; i++) {
    long row = row0 + rsub + 2 * i;
    if (row < N_NODES) {
      float o = RELU ? fmaxf(acc[i], 0.0f) : acc[i];
      out[row * HID + col] = o;
    }
  }
}

// ---------------- decoder precompute: u = z@dw1[0:128], v = z@dw1[128:256] ----------------
__global__ __launch_bounds__(256) void k_uv(const float* __restrict__ z,
                                            const float* __restrict__ dw1,
                                            float* __restrict__ u,
                                            float* __restrict__ v) {
  __shared__ float s_z[8][HID];
  const int col = threadIdx.x & 127;
  const int rsub = threadIdx.x >> 7;
  const long row0 = (long)blockIdx.x * 8;

  for (int idx = threadIdx.x; idx < 8 * HID; idx += 256) {
    int r = idx >> 7, k = idx & 127;
    long row = row0 + r;
    if (row < N_NODES) s_z[r][k] = z[row * HID + k];
  }
  __syncthreads();

  float au[4] = {0, 0, 0, 0}, av[4] = {0, 0, 0, 0};
  for (int k = 0; k < HID; k++) {
    float a = dw1[k * HID + col];
    float bb = dw1[(k + HID) * HID + col];
#pragma unroll
    for (int i = 0; i < 4; i++) {
      float zv = s_z[rsub + 2 * i][k];
      au[i] = fmaf(zv, a, au[i]);
      av[i] = fmaf(zv, bb, av[i]);
    }
  }

#pragma unroll
  for (int i = 0; i < 4; i++) {
    long row = row0 + rsub + 2 * i;
    if (row < N_NODES) {
      u[row * HID + col] = au[i];
      v[row * HID + col] = av[i];
    }
  }
}

// ---------------- per-label-edge decoder: out = relu(u[s]+v[d]+db1)·dw2 + db2 ----------------
__global__ __launch_bounds__(256) void k_edge(const int* __restrict__ ls,
                                              const int* __restrict__ ld,
                                              const float* __restrict__ u,
                                              const float* __restrict__ v,
                                              const float* __restrict__ db1,
                                              const float* __restrict__ dw2,
                                              const float* __restrict__ db2,
                                              float* __restrict__ out) {
  int lane = threadIdx.x & 63;
  long e = (long)blockIdx.x * 4 + (threadIdx.x >> 6);
  if (e >= N_LBL) return;
  int s = ls[e], d = ld[e];
  const float2 uu = *(const float2*)&u[(long)s * HID + lane * 2];
  const float2 vv = *(const float2*)&v[(long)d * HID + lane * 2];
  const float2 b = *(const float2*)&db1[lane * 2];
  const float2 w = *(const float2*)&dw2[lane * 2];
  float h0 = fmaxf(uu.x + vv.x + b.x, 0.0f);
  float h1 = fmaxf(uu.y + vv.y + b.y, 0.0f);
  float sum = h0 * w.x + h1 * w.y;
#pragma unroll
  for (int o = 32; o > 0; o >>= 1) sum += __shfl_down(sum, o);
  if (lane == 0) out[e] = sum + db2[0];
}

extern "C" void kernel_launch(void* const* d_in, const int* in_sizes, int n_in,
                              void* d_out, int out_size, void* d_ws, size_t ws_size,
                              hipStream_t stream) {
  const float* x   = (const float*)d_in[0];
  const int*   ei  = (const int*)d_in[1];
  const int*   eli = (const int*)d_in[2];
  const float* w1l = (const float*)d_in[3];
  const float* b1l = (const float*)d_in[4];
  const float* w1r = (const float*)d_in[5];
  const float* w2l = (const float*)d_in[6];
  const float* b2l = (const float*)d_in[7];
  const float* w2r = (const float*)d_in[8];
  const float* dw1 = (const float*)d_in[9];
  const float* db1 = (const float*)d_in[10];
  const float* dw2 = (const float*)d_in[11];
  const float* db2 = (const float*)d_in[12];
  float* out = (float*)d_out;

  // workspace layout (floats):
  //   deg/inv : [0, 131072)
  //   zbuf    : N*HID
  //   hbuf    : N*HID   (later reused as u)
  //   cbuf    : N*HID   (agg1 lives in its first N*64; then agg2; later v)
  float* ws   = (float*)d_ws;
  float* deg  = ws;
  float* zbuf = ws + 131072;
  float* hbuf = zbuf + (size_t)N_NODES * HID;
  float* cbuf = hbuf + (size_t)N_NODES * HID;
  float* agg1 = cbuf;

  const int* srcp = ei;
  const int* dstp = ei + N_EDGES;
  const int* lsp  = eli;
  const int* ldp  = eli + N_LBL;

  // degree + inv
  hipMemsetAsync(deg, 0, N_NODES * sizeof(float), stream);
  hipMemsetAsync(agg1, 0, (size_t)N_NODES * D_IN * sizeof(float), stream);
  k_deg<<<(N_EDGES + 255) / 256, 256, 0, stream>>>(dstp, deg);
  k_inv<<<(N_NODES + 255) / 256, 256, 0, stream>>>(deg);

  // layer 1
  k_scatter<64><<<(int)(((long)N_EDGES * 64) / 256), 256, 0, stream>>>(srcp, dstp, x, agg1);
  k_layer<64, true><<<(N_NODES + 7) / 8, 256, 0, stream>>>(agg1, deg, x, w1l, b1l, w1r, hbuf);

  // layer 2
  hipMemsetAsync(cbuf, 0, (size_t)N_NODES * HID * sizeof(float), stream);
  k_scatter<128><<<(int)(((long)N_EDGES * 128) / 256), 256, 0, stream>>>(srcp, dstp, hbuf, cbuf);
  k_layer<128, false><<<(N_NODES + 7) / 8, 256, 0, stream>>>(cbuf, deg, hbuf, w2l, b2l, w2r, zbuf);

  // decoder
  k_uv<<<(N_NODES + 7) / 8, 256, 0, stream>>>(zbuf, dw1, hbuf, cbuf);  // u->hbuf, v->cbuf
  k_edge<<<(N_LBL + 3) / 4, 256, 0, stream>>>(lsp, ldp, hbuf, cbuf, db1, dw2, db2, out);
}

// Round 2
// 1073.420 us; speedup vs baseline: 1.5081x; 1.5081x over previous
//
#include <hip/hip_runtime.h>

#define N_NODES 100000
#define D_IN 64
#define HID 128
#define N_EDGES 1600000
#define N_LBL 500000

// ---------------- degree histogram (int) ----------------
__global__ __launch_bounds__(256) void k_deg(const int* __restrict__ dst,
                                             int* __restrict__ deg) {
  int e = blockIdx.x * 256 + threadIdx.x;
  if (e < N_EDGES) atomicAdd(&deg[dst[e]], 1);
}

__global__ __launch_bounds__(256) void k_inv(const int* __restrict__ deg,
                                             float* __restrict__ inv) {
  int i = blockIdx.x * 256 + threadIdx.x;
  if (i < N_NODES) {
    int d = deg[i];
    inv[i] = d > 0 ? 1.0f / (float)d : 0.0f;
  }
}

// ---------------- exclusive scan over degrees (single block) ----------------
__global__ __launch_bounds__(1024) void k_scan(const int* __restrict__ deg,
                                               int* __restrict__ rowptr,
                                               int* __restrict__ cursor) {
  __shared__ int s[1024];
  __shared__ int s_carry;
  if (threadIdx.x == 0) s_carry = 0;
  __syncthreads();
  for (int base = 0; base < N_NODES; base += 1024) {
    int i = base + threadIdx.x;
    int v = (i < N_NODES) ? deg[i] : 0;
    s[threadIdx.x] = v;
    __syncthreads();
    // inclusive block scan
    for (int off = 1; off < 1024; off <<= 1) {
      int t = (threadIdx.x >= off) ? s[threadIdx.x - off] : 0;
      __syncthreads();
      s[threadIdx.x] += t;
      __syncthreads();
    }
    int incl = s[threadIdx.x];
    int excl = incl - v;
    int carry = s_carry;
    __syncthreads();  // everyone reads carry before it's updated
    if (threadIdx.x == 1023) s_carry = carry + s[1023];
    if (i < N_NODES) {
      rowptr[i] = carry + excl;
      cursor[i] = carry + excl;
    }
    __syncthreads();
  }
  if (threadIdx.x == 0) rowptr[N_NODES] = s_carry;
}

// ---------------- CSR fill: csr[pos] = src, pos via per-dst cursor ----------------
__global__ __launch_bounds__(256) void k_fill(const int* __restrict__ src,
                                              const int* __restrict__ dst,
                                              int* __restrict__ cursor,
                                              int* __restrict__ csr) {
  int e = blockIdx.x * 256 + threadIdx.x;
  if (e < N_EDGES) {
    int pos = atomicAdd(&cursor[dst[e]], 1);
    csr[pos] = src[e];
  }
}

// ---------------- gather aggregation: out[n] = mean over neighbors of feat[src] ----------------
template <int D>
__global__ __launch_bounds__(D) void k_agg(const int* __restrict__ rowptr,
                                           const int* __restrict__ csr,
                                           const float* __restrict__ feat,
                                           const float* __restrict__ inv,
                                           float* __restrict__ out) {
  const int n = blockIdx.x;
  const int tid = threadIdx.x;
  const int beg = rowptr[n], end = rowptr[n + 1];
  __shared__ int s_nbr[64];
  float acc = 0.0f;
  for (int j0 = beg; j0 < end; j0 += 64) {
    int cnt = min(64, end - j0);
    if (tid < cnt) s_nbr[tid] = csr[j0 + tid];
    __syncthreads();
    for (int j = 0; j < cnt; j++) acc += feat[(long)s_nbr[j] * D + tid];
    __syncthreads();
  }
  out[(long)n * D + tid] = acc * inv[n];
}

// ---------------- fused SAGE layer: out = act(mean@wl + bl + in@wr) ----------------
// Stages ALL inputs to LDS before writing, so `out` may alias `mean` (same rows).
template <int K, bool RELU>
__global__ __launch_bounds__(256) void k_layer(const float* __restrict__ mean,
                                               const float* __restrict__ xin,
                                               const float* __restrict__ wl,
                                               const float* __restrict__ bl,
                                               const float* __restrict__ wr,
                                               float* __restrict__ out) {
  __shared__ float s_a[8][K];
  __shared__ float s_x[8][K];
  const int col = threadIdx.x & 127;
  const int rsub = threadIdx.x >> 7;  // 0..1
  const long row0 = (long)blockIdx.x * 8;

  for (int idx = threadIdx.x; idx < 8 * K; idx += 256) {
    int r = idx / K, k = idx - r * K;
    long row = row0 + r;
    if (row < N_NODES) {
      s_a[r][k] = mean[row * K + k];
      s_x[r][k] = xin[row * K + k];
    }
  }
  __syncthreads();

  float acc[4];
  float b = bl[col];
#pragma unroll
  for (int i = 0; i < 4; i++) acc[i] = b;

  for (int k = 0; k < K; k++) {
    float wlv = wl[k * HID + col];
    float wrv = wr[k * HID + col];
#pragma unroll
    for (int i = 0; i < 4; i++) {
      int r = rsub + 2 * i;
      acc[i] = fmaf(s_a[r][k], wlv, acc[i]);
      acc[i] = fmaf(s_x[r][k], wrv, acc[i]);
    }
  }

#pragma unroll
  for (int i = 0; i < 4; i++) {
    long row = row0 + rsub + 2 * i;
    if (row < N_NODES) {
      float o = RELU ? fmaxf(acc[i], 0.0f) : acc[i];
      out[row * HID + col] = o;
    }
  }
}

// ---------------- decoder precompute: u = z@dw1[0:128] (in-place ok), v = z@dw1[128:256] ----------------
__global__ __launch_bounds__(256) void k_uv(const float* __restrict__ z,
                                            const float* __restrict__ dw1,
                                            float* __restrict__ u,
                                            float* __restrict__ v) {
  __shared__ float s_z[8][HID];
  const int col = threadIdx.x & 127;
  const int rsub = threadIdx.x >> 7;
  const long row0 = (long)blockIdx.x * 8;

  for (int idx = threadIdx.x; idx < 8 * HID; idx += 256) {
    int r = idx >> 7, k = idx & 127;
    long row = row0 + r;
    if (row < N_NODES) s_z[r][k] = z[row * HID + k];
  }
  __syncthreads();

  float au[4] = {0, 0, 0, 0}, av[4] = {0, 0, 0, 0};
  for (int k = 0; k < HID; k++) {
    float a = dw1[k * HID + col];
    float bb = dw1[(k + HID) * HID + col];
#pragma unroll
    for (int i = 0; i < 4; i++) {
      float zv = s_z[rsub + 2 * i][k];
      au[i] = fmaf(zv, a, au[i]);
      av[i] = fmaf(zv, bb, av[i]);
    }
  }

#pragma unroll
  for (int i = 0; i < 4; i++) {
    long row = row0 + rsub + 2 * i;
    if (row < N_NODES) {
      u[row * HID + col] = au[i];
      v[row * HID + col] = av[i];
    }
  }
}

// ---------------- per-label-edge decoder ----------------
__global__ __launch_bounds__(256) void k_edge(const int* __restrict__ ls,
                                              const int* __restrict__ ld,
                                              const float* __restrict__ u,
                                              const float* __restrict__ v,
                                              const float* __restrict__ db1,
                                              const float* __restrict__ dw2,
                                              const float* __restrict__ db2,
                                              float* __restrict__ out) {
  int lane = threadIdx.x & 63;
  long e = (long)blockIdx.x * 4 + (threadIdx.x >> 6);
  if (e >= N_LBL) return;
  int s = ls[e], d = ld[e];
  const float2 uu = *(const float2*)&u[(long)s * HID + lane * 2];
  const float2 vv = *(const float2*)&v[(long)d * HID + lane * 2];
  const float2 b = *(const float2*)&db1[lane * 2];
  const float2 w = *(const float2*)&dw2[lane * 2];
  float h0 = fmaxf(uu.x + vv.x + b.x, 0.0f);
  float h1 = fmaxf(uu.y + vv.y + b.y, 0.0f);
  float sum = h0 * w.x + h1 * w.y;
#pragma unroll
  for (int o = 32; o > 0; o >>= 1) sum += __shfl_down(sum, o);
  if (lane == 0) out[e] = sum + db2[0];
}

extern "C" void kernel_launch(void* const* d_in, const int* in_sizes, int n_in,
                              void* d_out, int out_size, void* d_ws, size_t ws_size,
                              hipStream_t stream) {
  const float* x   = (const float*)d_in[0];
  const int*   ei  = (const int*)d_in[1];
  const int*   eli = (const int*)d_in[2];
  const float* w1l = (const float*)d_in[3];
  const float* b1l = (const float*)d_in[4];
  const float* w1r = (const float*)d_in[5];
  const float* w2l = (const float*)d_in[6];
  const float* b2l = (const float*)d_in[7];
  const float* w2r = (const float*)d_in[8];
  const float* dw1 = (const float*)d_in[9];
  const float* db1 = (const float*)d_in[10];
  const float* dw2 = (const float*)d_in[11];
  const float* db2 = (const float*)d_in[12];
  float* out = (float*)d_out;

  // ---- workspace layout ----
  float* ws     = (float*)d_ws;
  float* inv    = ws;                         // 100000 f
  int*   deg_i  = (int*)(ws + 100000);        // 100000 i
  int*   rowptr = deg_i + 100000;             // 100008 i (padded)
  int*   cursor = rowptr + 100008;            // 100000 i
  int*   csr    = cursor + 100000;            // 1600000 i
  float* cbuf   = (float*)(csr + 1600000);    // 12.8M f  (mean1/mean2 -> z -> u)
  float* hbuf   = cbuf + (size_t)N_NODES * HID;  // 12.8M f (h -> v)

  const int* srcp = ei;
  const int* dstp = ei + N_EDGES;
  const int* lsp  = eli;
  const int* ldp  = eli + N_LBL;

  // ---- CSR build ----
  hipMemsetAsync(deg_i, 0, N_NODES * sizeof(int), stream);
  k_deg<<<(N_EDGES + 255) / 256, 256, 0, stream>>>(dstp, deg_i);
  k_inv<<<(N_NODES + 255) / 256, 256, 0, stream>>>(deg_i, inv);
  k_scan<<<1, 1024, 0, stream>>>(deg_i, rowptr, cursor);
  k_fill<<<(N_EDGES + 255) / 256, 256, 0, stream>>>(srcp, dstp, cursor, csr);

  // ---- layer 1: mean1 -> cbuf[:, :64]; h -> hbuf ----
  k_agg<64><<<N_NODES, 64, 0, stream>>>(rowptr, csr, x, inv, cbuf);
  k_layer<64, true><<<(N_NODES + 7) / 8, 256, 0, stream>>>(cbuf, x, w1l, b1l, w1r, hbuf);

  // ---- layer 2: mean2 -> cbuf; z -> cbuf (in-place over mean2) ----
  k_agg<128><<<N_NODES, 128, 0, stream>>>(rowptr, csr, hbuf, inv, cbuf);
  k_layer<128, false><<<(N_NODES + 7) / 8, 256, 0, stream>>>(cbuf, hbuf, w2l, b2l, w2r, cbuf);

  // ---- decoder: u -> cbuf (in-place over z), v -> hbuf ----
  k_uv<<<(N_NODES + 7) / 8, 256, 0, stream>>>(cbuf, dw1, cbuf, hbuf);
  k_edge<<<(N_LBL + 3) / 4, 256, 0, stream>>>(lsp, ldp, cbuf, hbuf, db1, dw2, db2, out);
}

// Round 3
// 868.020 us; speedup vs baseline: 1.8649x; 1.2366x over previous
//
#include <hip/hip_runtime.h>

#define N_NODES 100000
#define D_IN 64
#define HID 128
#define N_EDGES 1600000
#define N_LBL 500000

// ---------------- degree histogram (int) ----------------
__global__ __launch_bounds__(256) void k_deg(const int* __restrict__ dst,
                                             int* __restrict__ deg) {
  int e = blockIdx.x * 256 + threadIdx.x;
  if (e < N_EDGES) atomicAdd(&deg[dst[e]], 1);
}

__global__ __launch_bounds__(256) void k_inv(const int* __restrict__ deg,
                                             float* __restrict__ inv) {
  int i = blockIdx.x * 256 + threadIdx.x;
  if (i < N_NODES) {
    int d = deg[i];
    inv[i] = d > 0 ? 1.0f / (float)d : 0.0f;
  }
}

// ---------------- exclusive scan over degrees (single block, wave-shfl) ----------------
__global__ __launch_bounds__(1024) void k_scan(const int* __restrict__ deg,
                                               int* __restrict__ rowptr,
                                               int* __restrict__ cursor) {
  __shared__ int s_wsum[16];
  __shared__ int s_carry;
  const int lane = threadIdx.x & 63;
  const int wid = threadIdx.x >> 6;
  if (threadIdx.x == 0) s_carry = 0;
  __syncthreads();
  for (int base = 0; base < N_NODES; base += 1024) {
    int i = base + threadIdx.x;
    int v = (i < N_NODES) ? deg[i] : 0;
    int x = v;  // inclusive wave scan
#pragma unroll
    for (int off = 1; off < 64; off <<= 1) {
      int t = __shfl_up(x, off);
      if (lane >= off) x += t;
    }
    if (lane == 63) s_wsum[wid] = x;
    __syncthreads();
    if (wid == 0 && lane < 16) {
      int ws = s_wsum[lane];
      int y = ws;
#pragma unroll
      for (int off = 1; off < 16; off <<= 1) {
        int t = __shfl_up(y, off);
        if (lane >= off) y += t;
      }
      s_wsum[lane] = y - ws;  // exclusive wave offsets
    }
    __syncthreads();
    int t = s_carry + s_wsum[wid] + (x - v);
    if (i < N_NODES) { rowptr[i] = t; cursor[i] = t; }
    __syncthreads();
    if (threadIdx.x == 1023) s_carry = t + v;
    __syncthreads();
  }
  if (threadIdx.x == 0) rowptr[N_NODES] = s_carry;
}

// ---------------- CSR fill ----------------
__global__ __launch_bounds__(256) void k_fill(const int* __restrict__ src,
                                              const int* __restrict__ dst,
                                              int* __restrict__ cursor,
                                              int* __restrict__ csr) {
  int e = blockIdx.x * 256 + threadIdx.x;
  if (e < N_EDGES) {
    int pos = atomicAdd(&cursor[dst[e]], 1);
    csr[pos] = src[e];
  }
}

// ---------------- gather aggregation: wave per node ----------------
template <int D>
__global__ __launch_bounds__(256) void k_agg(const int* __restrict__ rowptr,
                                             const int* __restrict__ csr,
                                             const float* __restrict__ feat,
                                             const float* __restrict__ inv,
                                             float* __restrict__ out) {
  const int lane = threadIdx.x & 63;
  const int n = blockIdx.x * 4 + (threadIdx.x >> 6);  // grid exact: 25000*4
  const int beg = rowptr[n], end = rowptr[n + 1];
  if (D == 64) {
    float acc = 0.0f;
    int j = beg;
    for (; j + 4 <= end; j += 4) {
      int s0 = csr[j], s1 = csr[j + 1], s2 = csr[j + 2], s3 = csr[j + 3];
      float f0 = feat[(long)s0 * 64 + lane];
      float f1 = feat[(long)s1 * 64 + lane];
      float f2 = feat[(long)s2 * 64 + lane];
      float f3 = feat[(long)s3 * 64 + lane];
      acc += f0; acc += f1; acc += f2; acc += f3;
    }
    for (; j < end; ++j) acc += feat[(long)csr[j] * 64 + lane];
    out[(long)n * 64 + lane] = acc * inv[n];
  } else {
    float2 acc = {0.0f, 0.0f};
    int j = beg;
    for (; j + 4 <= end; j += 4) {
      int s0 = csr[j], s1 = csr[j + 1], s2 = csr[j + 2], s3 = csr[j + 3];
      float2 f0 = *(const float2*)&feat[(long)s0 * 128 + lane * 2];
      float2 f1 = *(const float2*)&feat[(long)s1 * 128 + lane * 2];
      float2 f2 = *(const float2*)&feat[(long)s2 * 128 + lane * 2];
      float2 f3 = *(const float2*)&feat[(long)s3 * 128 + lane * 2];
      acc.x += f0.x; acc.y += f0.y;
      acc.x += f1.x; acc.y += f1.y;
      acc.x += f2.x; acc.y += f2.y;
      acc.x += f3.x; acc.y += f3.y;
    }
    for (; j < end; ++j) {
      float2 f = *(const float2*)&feat[(long)csr[j] * 128 + lane * 2];
      acc.x += f.x; acc.y += f.y;
    }
    float iv = inv[n];
    float2 o = {acc.x * iv, acc.y * iv};
    *(float2*)&out[(long)n * 128 + lane * 2] = o;
  }
}

// ---------------- register-tiled fused SAGE layer ----------------
// Block: 256 thr, tile 32 rows x 128 cols, 4x4 per thread.
// out = act(mean@wl + bl + xin@wr); if DO_UV additionally:
//   z = that result (no relu), u = z@dw1[0:128] -> out, v = z@dw1[128:256] -> vout.
// Inputs fully staged to LDS before any write, so out may alias mean/xin rows.
template <int K, bool RELU, bool DO_UV>
__global__ __launch_bounds__(256) void k_layer(
    const float* __restrict__ mean, const float* __restrict__ xin,
    const float* __restrict__ wl, const float* __restrict__ bl,
    const float* __restrict__ wr, const float* __restrict__ dw1,
    float* __restrict__ out, float* __restrict__ vout) {
  constexpr int PAD = 36;  // stride 36 floats: keeps 16B alignment for b128 reads
  __shared__ float s_a[DO_UV ? HID : K][PAD];  // z reuses s_a in phase 2 (needs 128 rows)
  __shared__ float s_x[K][PAD];
  const int tx = threadIdx.x & 31;  // col group
  const int ty = threadIdx.x >> 5;  // row group
  const int row0 = blockIdx.x * 32; // grid exact: 3125*32 = 100000
  const int c0 = tx * 4;
  const int r0 = ty * 4;

  // stage 32 rows of mean and xin, transposed -> [k][row]
  {
    constexpr int KG = K / 4;
    for (int t = threadIdx.x; t < 32 * KG; t += 256) {
      int r = t / KG, kg = t % KG;
      float4 va = *(const float4*)&mean[(long)(row0 + r) * K + kg * 4];
      float4 vx = *(const float4*)&xin[(long)(row0 + r) * K + kg * 4];
      int k = kg * 4;
      s_a[k + 0][r] = va.x; s_a[k + 1][r] = va.y; s_a[k + 2][r] = va.z; s_a[k + 3][r] = va.w;
      s_x[k + 0][r] = vx.x; s_x[k + 1][r] = vx.y; s_x[k + 2][r] = vx.z; s_x[k + 3][r] = vx.w;
    }
  }
  __syncthreads();

  float acc[4][4];
  {
    float4 bv = *(const float4*)&bl[c0];
#pragma unroll
    for (int j = 0; j < 4; ++j) {
      acc[j][0] = bv.x; acc[j][1] = bv.y; acc[j][2] = bv.z; acc[j][3] = bv.w;
    }
  }

  for (int k = 0; k < K; ++k) {
    float4 av = *(const float4*)&s_a[k][r0];
    float4 xv = *(const float4*)&s_x[k][r0];
    float4 wlv = *(const float4*)&wl[(long)k * HID + c0];
    float4 wrv = *(const float4*)&wr[(long)k * HID + c0];
    float aj[4] = {av.x, av.y, av.z, av.w};
    float xj[4] = {xv.x, xv.y, xv.z, xv.w};
    float wli[4] = {wlv.x, wlv.y, wlv.z, wlv.w};
    float wri[4] = {wrv.x, wrv.y, wrv.z, wrv.w};
#pragma unroll
    for (int j = 0; j < 4; ++j)
#pragma unroll
      for (int i = 0; i < 4; ++i)
        acc[j][i] = fmaf(aj[j], wli[i], fmaf(xj[j], wri[i], acc[j][i]));
  }

  if (!DO_UV) {
#pragma unroll
    for (int j = 0; j < 4; ++j) {
      float4 o;
      o.x = RELU ? fmaxf(acc[j][0], 0.0f) : acc[j][0];
      o.y = RELU ? fmaxf(acc[j][1], 0.0f) : acc[j][1];
      o.z = RELU ? fmaxf(acc[j][2], 0.0f) : acc[j][2];
      o.w = RELU ? fmaxf(acc[j][3], 0.0f) : acc[j][3];
      *(float4*)&out[(long)(row0 + r0 + j) * HID + c0] = o;
    }
  } else {
    // z -> s_a transposed [col][row]
    __syncthreads();  // all phase-1 LDS reads done
#pragma unroll
    for (int j = 0; j < 4; ++j)
#pragma unroll
      for (int i = 0; i < 4; ++i)
        s_a[c0 + i][r0 + j] = acc[j][i];
    __syncthreads();

    float u[4][4], v[4][4];
#pragma unroll
    for (int j = 0; j < 4; ++j)
#pragma unroll
      for (int i = 0; i < 4; ++i) { u[j][i] = 0.0f; v[j][i] = 0.0f; }

    for (int k = 0; k < HID; ++k) {
      float4 zv = *(const float4*)&s_a[k][r0];
      float4 w1v = *(const float4*)&dw1[(long)k * HID + c0];
      float4 w2v = *(const float4*)&dw1[(long)(k + HID) * HID + c0];
      float zj[4] = {zv.x, zv.y, zv.z, zv.w};
      float w1i[4] = {w1v.x, w1v.y, w1v.z, w1v.w};
      float w2i[4] = {w2v.x, w2v.y, w2v.z, w2v.w};
#pragma unroll
      for (int j = 0; j < 4; ++j)
#pragma unroll
        for (int i = 0; i < 4; ++i) {
          u[j][i] = fmaf(zj[j], w1i[i], u[j][i]);
          v[j][i] = fmaf(zj[j], w2i[i], v[j][i]);
        }
    }

#pragma unroll
    for (int j = 0; j < 4; ++j) {
      float4 ou = {u[j][0], u[j][1], u[j][2], u[j][3]};
      float4 ov = {v[j][0], v[j][1], v[j][2], v[j][3]};
      *(float4*)&out[(long)(row0 + r0 + j) * HID + c0] = ou;
      *(float4*)&vout[(long)(row0 + r0 + j) * HID + c0] = ov;
    }
  }
}

// ---------------- per-label-edge decoder ----------------
__global__ __launch_bounds__(256) void k_edge(const int* __restrict__ ls,
                                              const int* __restrict__ ld,
                                              const float* __restrict__ u,
                                              const float* __restrict__ v,
                                              const float* __restrict__ db1,
                                              const float* __restrict__ dw2,
                                              const float* __restrict__ db2,
                                              float* __restrict__ out) {
  int lane = threadIdx.x & 63;
  long e = (long)blockIdx.x * 4 + (threadIdx.x >> 6);  // grid exact: 125000*4
  int s = ls[e], d = ld[e];
  const float2 uu = *(const float2*)&u[(long)s * HID + lane * 2];
  const float2 vv = *(const float2*)&v[(long)d * HID + lane * 2];
  const float2 b = *(const float2*)&db1[lane * 2];
  const float2 w = *(const float2*)&dw2[lane * 2];
  float h0 = fmaxf(uu.x + vv.x + b.x, 0.0f);
  float h1 = fmaxf(uu.y + vv.y + b.y, 0.0f);
  float sum = h0 * w.x + h1 * w.y;
#pragma unroll
  for (int o = 32; o > 0; o >>= 1) sum += __shfl_down(sum, o);
  if (lane == 0) out[e] = sum + db2[0];
}

extern "C" void kernel_launch(void* const* d_in, const int* in_sizes, int n_in,
                              void* d_out, int out_size, void* d_ws, size_t ws_size,
                              hipStream_t stream) {
  const float* x   = (const float*)d_in[0];
  const int*   ei  = (const int*)d_in[1];
  const int*   eli = (const int*)d_in[2];
  const float* w1l = (const float*)d_in[3];
  const float* b1l = (const float*)d_in[4];
  const float* w1r = (const float*)d_in[5];
  const float* w2l = (const float*)d_in[6];
  const float* b2l = (const float*)d_in[7];
  const float* w2r = (const float*)d_in[8];
  const float* dw1 = (const float*)d_in[9];
  const float* db1 = (const float*)d_in[10];
  const float* dw2 = (const float*)d_in[11];
  const float* db2 = (const float*)d_in[12];
  float* out = (float*)d_out;

  // ---- workspace layout ----
  float* ws     = (float*)d_ws;
  float* inv    = ws;                             // 100000 f
  int*   deg_i  = (int*)(ws + 100000);            // 100000 i
  int*   rowptr = deg_i + 100000;                 // 100008 i
  int*   cursor = rowptr + 100008;                // 100000 i
  int*   csr    = cursor + 100000;                // 1600000 i
  float* cbuf   = (float*)(csr + 1600000);        // N*HID f (mean1/mean2 -> u)
  float* hbuf   = cbuf + (size_t)N_NODES * HID;   // N*HID f (h -> v)

  const int* srcp = ei;
  const int* dstp = ei + N_EDGES;
  const int* lsp  = eli;
  const int* ldp  = eli + N_LBL;

  // ---- CSR build ----
  hipMemsetAsync(deg_i, 0, N_NODES * sizeof(int), stream);
  k_deg<<<(N_EDGES + 255) / 256, 256, 0, stream>>>(dstp, deg_i);
  k_inv<<<(N_NODES + 255) / 256, 256, 0, stream>>>(deg_i, inv);
  k_scan<<<1, 1024, 0, stream>>>(deg_i, rowptr, cursor);
  k_fill<<<(N_EDGES + 255) / 256, 256, 0, stream>>>(srcp, dstp, cursor, csr);

  // ---- layer 1: mean1 -> cbuf (64 cols); h = relu(...) -> hbuf ----
  k_agg<64><<<N_NODES / 4, 256, 0, stream>>>(rowptr, csr, x, inv, cbuf);
  k_layer<64, true, false><<<N_NODES / 32, 256, 0, stream>>>(
      cbuf, x, w1l, b1l, w1r, nullptr, hbuf, nullptr);

  // ---- layer 2 + decoder-precompute fused:
  //      mean2 -> cbuf; z in LDS; u -> cbuf, v -> hbuf ----
  k_agg<128><<<N_NODES / 4, 256, 0, stream>>>(rowptr, csr, hbuf, inv, cbuf);
  k_layer<128, false, true><<<N_NODES / 32, 256, 0, stream>>>(
      cbuf, hbuf, w2l, b2l, w2r, dw1, cbuf, hbuf);

  // ---- decoder edge MLP ----
  k_edge<<<N_LBL / 4, 256, 0, stream>>>(lsp, ldp, cbuf, hbuf, db1, dw2, db2, out);
}